// Round 1
// baseline (1953.634 us; speedup 1.0000x reference)
//
#include <hip/hip_runtime.h>

// ---------- common ----------
typedef __bf16 bfv8 __attribute__((ext_vector_type(8)));
typedef float f32x4 __attribute__((ext_vector_type(4)));

#define DMODEL 2048
#define NHEADS 16
#define HEADD 128
#define SEQ 2048
#define BATCH 2
#define MROWS (BATCH * SEQ)   // 4096

__device__ __forceinline__ unsigned short f2bf(float f) {
    unsigned int x = __float_as_uint(f);
    x += 0x7fffu + ((x >> 16) & 1u);   // round-to-nearest-even
    return (unsigned short)(x >> 16);
}

// ---------- fp32 -> bf16 convert ----------
__global__ __launch_bounds__(256) void cvt_f2b(const float* __restrict__ s,
                                               unsigned short* __restrict__ d, int n) {
    int i = (blockIdx.x * 256 + threadIdx.x) * 4;
    if (i >= n) return;
    float4 v = *(const float4*)(s + i);
    ushort4 o;
    o.x = f2bf(v.x); o.y = f2bf(v.y); o.z = f2bf(v.z); o.w = f2bf(v.w);
    *(ushort4*)(d + i) = o;
}

// ---------- bf16 MFMA GEMM:  C[M][N] = A[M][K] * Bw[N][K]^T  (fp32 out) ----------
#define GBM 128
#define GBN 128
#define GBK 64
#define GLDK 72   // +8 bf16 pad -> row stride 144 B -> <=2-way LDS conflicts

__global__ __launch_bounds__(256) void gemm_bt_bf16(const unsigned short* __restrict__ A,
                                                    const unsigned short* __restrict__ Bw,
                                                    float* __restrict__ C,
                                                    int M, int N, int K) {
    __shared__ unsigned short As[GBM][GLDK];
    __shared__ unsigned short Bs[GBN][GLDK];
    int tid  = threadIdx.x;
    int bm   = blockIdx.y * GBM, bn = blockIdx.x * GBN;
    int wave = tid >> 6, lane = tid & 63;
    int wm   = (wave >> 1) * 64, wn = (wave & 1) * 64;
    int lr   = lane & 15;          // m/n within 16
    int lk   = (lane >> 4) * 8;    // k-chunk offset

    f32x4 acc[4][4];
    f32x4 z = {0.f, 0.f, 0.f, 0.f};
#pragma unroll
    for (int i = 0; i < 4; ++i)
#pragma unroll
        for (int j = 0; j < 4; ++j) acc[i][j] = z;

    for (int k0 = 0; k0 < K; k0 += GBK) {
        int4 av[4], bv[4];
#pragma unroll
        for (int i = 0; i < 4; ++i) {
            int c = i * 256 + tid;
            int row = c >> 3, cc = (c & 7) * 8;
            av[i] = *(const int4*)(A  + (size_t)(bm + row) * K + k0 + cc);
            bv[i] = *(const int4*)(Bw + (size_t)(bn + row) * K + k0 + cc);
        }
        __syncthreads();   // previous iter's LDS reads done
#pragma unroll
        for (int i = 0; i < 4; ++i) {
            int c = i * 256 + tid;
            int row = c >> 3, cc = (c & 7) * 8;
            *(int4*)&As[row][cc] = av[i];
            *(int4*)&Bs[row][cc] = bv[i];
        }
        __syncthreads();
#pragma unroll
        for (int kk = 0; kk < GBK; kk += 32) {
            bfv8 af[4], bf[4];
#pragma unroll
            for (int i = 0; i < 4; ++i) af[i] = *(const bfv8*)&As[wm + i * 16 + lr][kk + lk];
#pragma unroll
            for (int j = 0; j < 4; ++j) bf[j] = *(const bfv8*)&Bs[wn + j * 16 + lr][kk + lk];
#pragma unroll
            for (int i = 0; i < 4; ++i)
#pragma unroll
                for (int j = 0; j < 4; ++j)
                    acc[i][j] = __builtin_amdgcn_mfma_f32_16x16x32_bf16(af[i], bf[j], acc[i][j], 0, 0, 0);
        }
    }
    int orow0 = bm + wm + (lane >> 4) * 4;
    int ocol0 = bn + wn + (lane & 15);
#pragma unroll
    for (int i = 0; i < 4; ++i)
#pragma unroll
        for (int j = 0; j < 4; ++j)
#pragma unroll
            for (int r = 0; r < 4; ++r)
                C[(size_t)(orow0 + i * 16 + r) * N + ocol0 + j * 16] = acc[i][j][r];
}

// ---------- RoPE + per-head LayerNorm (in place, fp32) ----------
// one wave per (b,s,h) row of 128; lane handles interleaved pair (2*lane, 2*lane+1)
__global__ __launch_bounds__(256) void rope_ln(float* __restrict__ t, const float* __restrict__ w) {
    int gr   = blockIdx.x * 4 + (threadIdx.x >> 6);  // head-row index [0, M*H)
    int lane = threadIdx.x & 63;
    int m = gr >> 4;          // / NHEADS
    int h = gr & 15;
    int s = m & (SEQ - 1);    // position
    float* p = t + (size_t)m * DMODEL + h * HEADD + lane * 2;
    float2 xv = *(float2*)p;
    float inv = powf(10000.0f, -(float)lane * (1.0f / 64.0f));
    float ang = (float)s * inv;
    float sn, c;
    sincosf(ang, &sn, &c);
    float y0 = xv.x * c - xv.y * sn;
    float y1 = xv.x * sn + xv.y * c;
    float sum = y0 + y1;
    float sq  = y0 * y0 + y1 * y1;
#pragma unroll
    for (int o = 32; o >= 1; o >>= 1) {
        sum += __shfl_xor(sum, o);
        sq  += __shfl_xor(sq, o);
    }
    float mu  = sum * (1.0f / 128.0f);
    float var = sq * (1.0f / 128.0f) - mu * mu;
    float rs  = rsqrtf(var + 1e-5f);
    float2 wv = *(const float2*)(w + lane * 2);
    float2 ov;
    ov.x = (y0 - mu) * rs * wv.x;
    ov.y = (y1 - mu) * rs * wv.y;
    *(float2*)p = ov;
}

// ---------- fp32 flash attention (sliding window), bf16 output ----------
#define QT 32
#define KTL 32
#define APAD 132   // 128 + 4 floats pad
#define SPAD 36

__global__ __launch_bounds__(256) void attn_fwd(const float* __restrict__ q,
                                                const float* __restrict__ k,
                                                const float* __restrict__ v,
                                                unsigned short* __restrict__ ob,
                                                const int* __restrict__ wptr) {
    __shared__ float Qs[QT][APAD];
    __shared__ float Ks[KTL][APAD];
    __shared__ float Vs[KTL][APAD];
    __shared__ float Ss[QT][SPAD];
    int tid = threadIdx.x;
    int b = blockIdx.z, h = blockIdx.y;
    int q0 = blockIdx.x * QT;
    int W = *wptr;
    const size_t RS = DMODEL;
    const float* qb = q + ((size_t)b * SEQ) * RS + h * HEADD;
    const float* kb = k + ((size_t)b * SEQ) * RS + h * HEADD;
    const float* vb = v + ((size_t)b * SEQ) * RS + h * HEADD;

#pragma unroll
    for (int i = 0; i < 4; ++i) {
        int c = i * 256 + tid;
        int r = c >> 5, c4 = (c & 31) * 4;
        *(float4*)&Qs[r][c4] = *(const float4*)(qb + (size_t)(q0 + r) * RS + c4);
    }

    float O[4][4] = {};
    float mrow = -1e30f, lrow = 0.0f;
    int r  = tid >> 3;   // q-row this thread owns (0..31) in all phases
    int dg = tid & 7;    // 8-lane group position

    int kt_lo = max(0, q0 - W) & ~(KTL - 1);
    const float scale = 0.08838834764831845f;  // 1/sqrt(128)

    for (int kt = kt_lo; kt <= q0 + QT - 1; kt += KTL) {
        __syncthreads();   // everyone done with previous K/V tile
#pragma unroll
        for (int i = 0; i < 4; ++i) {
            int c = i * 256 + tid;
            int rr = c >> 5, c4 = (c & 31) * 4;
            *(float4*)&Ks[rr][c4] = *(const float4*)(kb + (size_t)(kt + rr) * RS + c4);
            *(float4*)&Vs[rr][c4] = *(const float4*)(vb + (size_t)(kt + rr) * RS + c4);
        }
        __syncthreads();

        // scores: row r, cols dg + 8*cc
        float sc[4] = {0.f, 0.f, 0.f, 0.f};
#pragma unroll
        for (int d4 = 0; d4 < HEADD / 4; ++d4) {
            float4 qv = *(const float4*)&Qs[r][d4 * 4];
#pragma unroll
            for (int cc = 0; cc < 4; ++cc) {
                float4 kv = *(const float4*)&Ks[dg + 8 * cc][d4 * 4];
                sc[cc] += qv.x * kv.x + qv.y * kv.y + qv.z * kv.z + qv.w * kv.w;
            }
        }
        int qi = q0 + r;
#pragma unroll
        for (int cc = 0; cc < 4; ++cc) {
            int kj = kt + dg + 8 * cc;
            bool okm = (kj <= qi) && (kj >= qi - W);
            sc[cc] = okm ? sc[cc] * scale : -1e30f;
        }
        // online softmax (8-lane shuffle group per row; same wave throughout)
        float lm = fmaxf(fmaxf(sc[0], sc[1]), fmaxf(sc[2], sc[3]));
        lm = fmaxf(lm, __shfl_xor(lm, 1));
        lm = fmaxf(lm, __shfl_xor(lm, 2));
        lm = fmaxf(lm, __shfl_xor(lm, 4));
        float mnew  = fmaxf(mrow, lm);
        float alpha = __expf(mrow - mnew);
        float ls = 0.0f;
#pragma unroll
        for (int cc = 0; cc < 4; ++cc) {
            float p = __expf(sc[cc] - mnew);
            Ss[r][dg + 8 * cc] = p;   // same-wave producers/consumers only
            ls += p;
        }
        ls += __shfl_xor(ls, 1);
        ls += __shfl_xor(ls, 2);
        ls += __shfl_xor(ls, 4);
        lrow = lrow * alpha + ls;
        mrow = mnew;
#pragma unroll
        for (int g = 0; g < 4; ++g)
#pragma unroll
            for (int e = 0; e < 4; ++e) O[g][e] *= alpha;
        // PV: dims d = dg*4 + 32*g + e  (bank-quad starts 4*dg -> conflict-free)
#pragma unroll
        for (int j = 0; j < KTL; ++j) {
            float p = Ss[r][j];
#pragma unroll
            for (int g = 0; g < 4; ++g) {
                float4 vv = *(const float4*)&Vs[j][dg * 4 + 32 * g];
                O[g][0] += p * vv.x;
                O[g][1] += p * vv.y;
                O[g][2] += p * vv.z;
                O[g][3] += p * vv.w;
            }
        }
    }
    float invl = 1.0f / lrow;
    unsigned short* op = ob + ((size_t)(b * SEQ + q0 + r)) * RS + h * HEADD;
#pragma unroll
    for (int g = 0; g < 4; ++g) {
        ushort4 o4;
        o4.x = f2bf(O[g][0] * invl);
        o4.y = f2bf(O[g][1] * invl);
        o4.z = f2bf(O[g][2] * invl);
        o4.w = f2bf(O[g][3] * invl);
        *(ushort4*)(op + dg * 4 + 32 * g) = o4;
    }
}

// ---------- launch ----------
extern "C" void kernel_launch(void* const* d_in, const int* in_sizes, int n_in,
                              void* d_out, int out_size, void* d_ws, size_t ws_size,
                              hipStream_t stream) {
    const float* x   = (const float*)d_in[0];
    const float* wq  = (const float*)d_in[1];
    const float* wk  = (const float*)d_in[2];
    const float* wv  = (const float*)d_in[3];
    const float* wo  = (const float*)d_in[4];
    const float* qnw = (const float*)d_in[5];
    const float* knw = (const float*)d_in[6];
    const int*   wsz = (const int*)d_in[7];
    float* out = (float*)d_out;

    // workspace layout (151 MB total)
    char* ws = (char*)d_ws;
    unsigned short* xb  = (unsigned short*)(ws);               // 16.7 MB (x bf16, reused for attn-out bf16)
    unsigned short* wqb = (unsigned short*)(ws + 16777216);    // 8.4 MB
    unsigned short* wkb = (unsigned short*)(ws + 25165824);
    unsigned short* wvb = (unsigned short*)(ws + 33554432);
    unsigned short* wob = (unsigned short*)(ws + 41943040);
    float* qf = (float*)(ws + 50331648);                       // 33.5 MB each
    float* kf = (float*)(ws + 83886080);
    float* vf = (float*)(ws + 117440512);

    cvt_f2b<<<8192, 256, 0, stream>>>(x,  xb,  MROWS * DMODEL);
    cvt_f2b<<<4096, 256, 0, stream>>>(wq, wqb, DMODEL * DMODEL);
    cvt_f2b<<<4096, 256, 0, stream>>>(wk, wkb, DMODEL * DMODEL);
    cvt_f2b<<<4096, 256, 0, stream>>>(wv, wvb, DMODEL * DMODEL);
    cvt_f2b<<<4096, 256, 0, stream>>>(wo, wob, DMODEL * DMODEL);

    dim3 gg(DMODEL / GBN, MROWS / GBM);   // (16, 32)
    gemm_bt_bf16<<<gg, 256, 0, stream>>>(xb, wqb, qf, MROWS, DMODEL, DMODEL);
    gemm_bt_bf16<<<gg, 256, 0, stream>>>(xb, wkb, kf, MROWS, DMODEL, DMODEL);
    gemm_bt_bf16<<<gg, 256, 0, stream>>>(xb, wvb, vf, MROWS, DMODEL, DMODEL);

    rope_ln<<<MROWS * NHEADS / 4, 256, 0, stream>>>(qf, qnw);
    rope_ln<<<MROWS * NHEADS / 4, 256, 0, stream>>>(kf, knw);

    attn_fwd<<<dim3(SEQ / QT, NHEADS, BATCH), 256, 0, stream>>>(qf, kf, vf, xb, wsz);

    gemm_bt_bf16<<<gg, 256, 0, stream>>>(xb, wob, out, MROWS, DMODEL, DMODEL);
}

// Round 2
// 976.773 us; speedup vs baseline: 2.0001x; 2.0001x over previous
//
#include <hip/hip_runtime.h>

// ---------- common ----------
typedef __bf16 bfv8 __attribute__((ext_vector_type(8)));
typedef float f32x4 __attribute__((ext_vector_type(4)));

#define DMODEL 2048
#define NHEADS 16
#define HEADD 128
#define SEQ 2048
#define BATCH 2
#define MROWS (BATCH * SEQ)   // 4096

__device__ __forceinline__ unsigned short f2bf(float f) {
    unsigned int x = __float_as_uint(f);
    x += 0x7fffu + ((x >> 16) & 1u);   // round-to-nearest-even
    return (unsigned short)(x >> 16);
}

// ---------- fp32 -> bf16 convert ----------
__global__ __launch_bounds__(256) void cvt_f2b(const float* __restrict__ s,
                                               unsigned short* __restrict__ d, int n) {
    int i = (blockIdx.x * 256 + threadIdx.x) * 4;
    if (i >= n) return;
    float4 v = *(const float4*)(s + i);
    ushort4 o;
    o.x = f2bf(v.x); o.y = f2bf(v.y); o.z = f2bf(v.z); o.w = f2bf(v.w);
    *(ushort4*)(d + i) = o;
}

// ---------- bf16 MFMA GEMM:  C[M][N] = A[M][K] * Bw[N][K]^T  (fp32 out) ----------
#define GBM 128
#define GBN 128
#define GBK 64
#define GLDK 72   // +8 bf16 pad -> 2-way LDS conflicts only (free)

__global__ __launch_bounds__(256) void gemm_bt_bf16(const unsigned short* __restrict__ A,
                                                    const unsigned short* __restrict__ Bw,
                                                    float* __restrict__ C,
                                                    int M, int N, int K) {
    __shared__ unsigned short As[GBM][GLDK];
    __shared__ unsigned short Bs[GBN][GLDK];
    int tid  = threadIdx.x;
    int bm   = blockIdx.y * GBM, bn = blockIdx.x * GBN;
    int wave = tid >> 6, lane = tid & 63;
    int wm   = (wave >> 1) * 64, wn = (wave & 1) * 64;
    int lr   = lane & 15;
    int lk   = (lane >> 4) * 8;

    f32x4 acc[4][4];
    f32x4 z = {0.f, 0.f, 0.f, 0.f};
#pragma unroll
    for (int i = 0; i < 4; ++i)
#pragma unroll
        for (int j = 0; j < 4; ++j) acc[i][j] = z;

    for (int k0 = 0; k0 < K; k0 += GBK) {
        int4 av[4], bv[4];
#pragma unroll
        for (int i = 0; i < 4; ++i) {
            int c = i * 256 + tid;
            int row = c >> 3, cc = (c & 7) * 8;
            av[i] = *(const int4*)(A  + (size_t)(bm + row) * K + k0 + cc);
            bv[i] = *(const int4*)(Bw + (size_t)(bn + row) * K + k0 + cc);
        }
        __syncthreads();
#pragma unroll
        for (int i = 0; i < 4; ++i) {
            int c = i * 256 + tid;
            int row = c >> 3, cc = (c & 7) * 8;
            *(int4*)&As[row][cc] = av[i];
            *(int4*)&Bs[row][cc] = bv[i];
        }
        __syncthreads();
#pragma unroll
        for (int kk = 0; kk < GBK; kk += 32) {
            bfv8 af[4], bf[4];
#pragma unroll
            for (int i = 0; i < 4; ++i) af[i] = *(const bfv8*)&As[wm + i * 16 + lr][kk + lk];
#pragma unroll
            for (int j = 0; j < 4; ++j) bf[j] = *(const bfv8*)&Bs[wn + j * 16 + lr][kk + lk];
#pragma unroll
            for (int i = 0; i < 4; ++i)
#pragma unroll
                for (int j = 0; j < 4; ++j)
                    acc[i][j] = __builtin_amdgcn_mfma_f32_16x16x32_bf16(af[i], bf[j], acc[i][j], 0, 0, 0);
        }
    }
    int orow0 = bm + wm + (lane >> 4) * 4;
    int ocol0 = bn + wn + (lane & 15);
#pragma unroll
    for (int i = 0; i < 4; ++i)
#pragma unroll
        for (int j = 0; j < 4; ++j)
#pragma unroll
            for (int r = 0; r < 4; ++r)
                C[(size_t)(orow0 + i * 16 + r) * N + ocol0 + j * 16] = acc[i][j][r];
}

// ---------- same GEMM, bf16 output written TRANSPOSED per head: Vt[(b,h,d)][s] ----------
__global__ __launch_bounds__(256) void gemm_bt_vt(const unsigned short* __restrict__ A,
                                                  const unsigned short* __restrict__ Bw,
                                                  unsigned short* __restrict__ VT,
                                                  int M, int N, int K) {
    __shared__ unsigned short As[GBM][GLDK];
    __shared__ unsigned short Bs[GBN][GLDK];
    int tid  = threadIdx.x;
    int bm   = blockIdx.y * GBM, bn = blockIdx.x * GBN;
    int wave = tid >> 6, lane = tid & 63;
    int wm   = (wave >> 1) * 64, wn = (wave & 1) * 64;
    int lr   = lane & 15;
    int lk   = (lane >> 4) * 8;

    f32x4 acc[4][4];
    f32x4 z = {0.f, 0.f, 0.f, 0.f};
#pragma unroll
    for (int i = 0; i < 4; ++i)
#pragma unroll
        for (int j = 0; j < 4; ++j) acc[i][j] = z;

    for (int k0 = 0; k0 < K; k0 += GBK) {
        int4 av[4], bv[4];
#pragma unroll
        for (int i = 0; i < 4; ++i) {
            int c = i * 256 + tid;
            int row = c >> 3, cc = (c & 7) * 8;
            av[i] = *(const int4*)(A  + (size_t)(bm + row) * K + k0 + cc);
            bv[i] = *(const int4*)(Bw + (size_t)(bn + row) * K + k0 + cc);
        }
        __syncthreads();
#pragma unroll
        for (int i = 0; i < 4; ++i) {
            int c = i * 256 + tid;
            int row = c >> 3, cc = (c & 7) * 8;
            *(int4*)&As[row][cc] = av[i];
            *(int4*)&Bs[row][cc] = bv[i];
        }
        __syncthreads();
#pragma unroll
        for (int kk = 0; kk < GBK; kk += 32) {
            bfv8 af[4], bf[4];
#pragma unroll
            for (int i = 0; i < 4; ++i) af[i] = *(const bfv8*)&As[wm + i * 16 + lr][kk + lk];
#pragma unroll
            for (int j = 0; j < 4; ++j) bf[j] = *(const bfv8*)&Bs[wn + j * 16 + lr][kk + lk];
#pragma unroll
            for (int i = 0; i < 4; ++i)
#pragma unroll
                for (int j = 0; j < 4; ++j)
                    acc[i][j] = __builtin_amdgcn_mfma_f32_16x16x32_bf16(af[i], bf[j], acc[i][j], 0, 0, 0);
        }
    }
    // transposed bf16 epilogue: 4 consecutive C-rows (= seq positions) -> ushort4 along Vt's fast axis
    int orow0 = bm + wm + (lane >> 4) * 4;
    int ocol0 = bn + wn + (lane & 15);
#pragma unroll
    for (int i = 0; i < 4; ++i) {
        int row = orow0 + i * 16;
        int bb = row >> 11, ss = row & (SEQ - 1);
#pragma unroll
        for (int j = 0; j < 4; ++j) {
            int col = ocol0 + j * 16;
            int hh = col >> 7, dd = col & (HEADD - 1);
            ushort4 o4;
            o4.x = f2bf(acc[i][j][0]);
            o4.y = f2bf(acc[i][j][1]);
            o4.z = f2bf(acc[i][j][2]);
            o4.w = f2bf(acc[i][j][3]);
            *(ushort4*)(VT + ((size_t)((bb * NHEADS + hh) * HEADD + dd)) * SEQ + ss) = o4;
        }
    }
}

// ---------- RoPE + per-head LayerNorm: fp32 in -> bf16 out ----------
__global__ __launch_bounds__(256) void rope_ln_b(const float* __restrict__ t,
                                                 const float* __restrict__ w,
                                                 unsigned short* __restrict__ ob) {
    int gr   = blockIdx.x * 4 + (threadIdx.x >> 6);
    int lane = threadIdx.x & 63;
    int m = gr >> 4;
    int h = gr & 15;
    int s = m & (SEQ - 1);
    const float* p = t + (size_t)m * DMODEL + h * HEADD + lane * 2;
    float2 xv = *(const float2*)p;
    float inv = powf(10000.0f, -(float)lane * (1.0f / 64.0f));
    float ang = (float)s * inv;
    float sn, c;
    sincosf(ang, &sn, &c);
    float y0 = xv.x * c - xv.y * sn;
    float y1 = xv.x * sn + xv.y * c;
    float sum = y0 + y1;
    float sq  = y0 * y0 + y1 * y1;
#pragma unroll
    for (int o = 32; o >= 1; o >>= 1) {
        sum += __shfl_xor(sum, o);
        sq  += __shfl_xor(sq, o);
    }
    float mu  = sum * (1.0f / 128.0f);
    float var = sq * (1.0f / 128.0f) - mu * mu;
    float rs  = rsqrtf(var + 1e-5f);
    float2 wv = *(const float2*)(w + lane * 2);
    ushort2 ov;
    ov.x = f2bf((y0 - mu) * rs * wv.x);
    ov.y = f2bf((y1 - mu) * rs * wv.y);
    *(ushort2*)(ob + (size_t)m * DMODEL + h * HEADD + lane * 2) = ov;
}

// ---------- bf16 MFMA flash attention (sliding window) ----------
#define AQT 64
#define AKT 64
#define KSP 136   // 128+8 pad: row stride 68 words -> 2-way (free)
#define VTP 72    // 64+8 pad
#define PSP 72    // 64+8 pad

__global__ __launch_bounds__(256) void attn_mfma(const unsigned short* __restrict__ qb,
                                                 const unsigned short* __restrict__ kb,
                                                 const unsigned short* __restrict__ vt,
                                                 unsigned short* __restrict__ ob,
                                                 const int* __restrict__ wptr) {
    __shared__ unsigned short Ks[AKT][KSP];
    __shared__ unsigned short Vs[HEADD][VTP];
    __shared__ unsigned short Ps[4][16][PSP];
    int tid  = threadIdx.x;
    int wq   = tid >> 6, lane = tid & 63;
    int lm   = lane & 15, lg = lane >> 4;
    int b = blockIdx.z, h = blockIdx.y;
    int q0 = blockIdx.x * AQT;
    int W = *wptr;

    // Q A-fragments (16 queries/wave), from bf16 rope+LN'd Q
    bfv8 qa[4];
    {
        const unsigned short* qp = qb + (size_t)(b * SEQ + q0 + wq * 16 + lm) * DMODEL + h * HEADD + lg * 8;
#pragma unroll
        for (int kk = 0; kk < 4; ++kk) qa[kk] = *(const bfv8*)(qp + kk * 32);
    }

    f32x4 o[8];
    f32x4 z = {0.f, 0.f, 0.f, 0.f};
#pragma unroll
    for (int n = 0; n < 8; ++n) o[n] = z;
    float mrow[4], lrow[4];
#pragma unroll
    for (int r = 0; r < 4; ++r) { mrow[r] = -1e30f; lrow[r] = 0.f; }

    const unsigned short* kbase = kb + (size_t)(b * SEQ) * DMODEL + h * HEADD;
    const unsigned short* vbase = vt + (size_t)((b * NHEADS + h) * HEADD) * SEQ;

    int kt_lo = max(0, q0 - W) & ~(AKT - 1);
    const float scale = 0.08838834764831845f;  // 1/sqrt(128)
    int qi0 = q0 + wq * 16 + lg * 4;           // C-layout base row for this lane

    for (int kt = kt_lo; kt < q0 + AQT; kt += AKT) {
        __syncthreads();
#pragma unroll
        for (int i = 0; i < 4; ++i) {   // K tile: 64 rows x 128 bf16
            int c = i * 256 + tid;
            int row = c >> 4, ch = c & 15;
            *(int4*)&Ks[row][ch * 8] = *(const int4*)(kbase + (size_t)(kt + row) * DMODEL + ch * 8);
        }
#pragma unroll
        for (int i = 0; i < 4; ++i) {   // Vt tile: 128 rows x 64 bf16
            int c = i * 256 + tid;
            int row = c >> 3, ch = c & 7;
            *(int4*)&Vs[row][ch * 8] = *(const int4*)(vbase + (size_t)row * SEQ + kt + ch * 8);
        }
        __syncthreads();

        // scores S = Q K^T  (16 x 64 per wave)
        f32x4 s[4];
#pragma unroll
        for (int j = 0; j < 4; ++j) s[j] = z;
#pragma unroll
        for (int j = 0; j < 4; ++j)
#pragma unroll
            for (int kk = 0; kk < 4; ++kk) {
                bfv8 kf = *(const bfv8*)&Ks[j * 16 + lm][kk * 32 + lg * 8];
                s[j] = __builtin_amdgcn_mfma_f32_16x16x32_bf16(qa[kk], kf, s[j], 0, 0, 0);
            }
        // mask + scale
#pragma unroll
        for (int j = 0; j < 4; ++j) {
            int kj = kt + j * 16 + lm;
#pragma unroll
            for (int r = 0; r < 4; ++r) {
                bool ok = (kj <= qi0 + r) && (kj >= qi0 + r - W);
                s[j][r] = ok ? s[j][r] * scale : -1e30f;
            }
        }
        // online softmax (per-lane rows qi0+r; reduce across lane&15)
        float mx[4];
#pragma unroll
        for (int r = 0; r < 4; ++r)
            mx[r] = fmaxf(fmaxf(s[0][r], s[1][r]), fmaxf(s[2][r], s[3][r]));
#pragma unroll
        for (int msk = 1; msk <= 8; msk <<= 1)
#pragma unroll
            for (int r = 0; r < 4; ++r) mx[r] = fmaxf(mx[r], __shfl_xor(mx[r], msk));
        float alpha[4];
#pragma unroll
        for (int r = 0; r < 4; ++r) {
            float mnew = fmaxf(mrow[r], mx[r]);
            alpha[r] = __expf(mrow[r] - mnew);
            mrow[r] = mnew;
        }
        float rsum[4] = {0.f, 0.f, 0.f, 0.f};
#pragma unroll
        for (int j = 0; j < 4; ++j)
#pragma unroll
            for (int r = 0; r < 4; ++r) {
                float p = __expf(s[j][r] - mrow[r]);
                rsum[r] += p;
                Ps[wq][lg * 4 + r][j * 16 + lm] = f2bf(p);   // wave-private region
            }
#pragma unroll
        for (int msk = 1; msk <= 8; msk <<= 1)
#pragma unroll
            for (int r = 0; r < 4; ++r) rsum[r] += __shfl_xor(rsum[r], msk);
#pragma unroll
        for (int r = 0; r < 4; ++r) lrow[r] = lrow[r] * alpha[r] + rsum[r];
        // rescale O then accumulate P·V
#pragma unroll
        for (int n = 0; n < 8; ++n)
#pragma unroll
            for (int r = 0; r < 4; ++r) o[n][r] *= alpha[r];
#pragma unroll
        for (int k2 = 0; k2 < 2; ++k2) {
            bfv8 pa = *(const bfv8*)&Ps[wq][lm][k2 * 32 + lg * 8];
#pragma unroll
            for (int n = 0; n < 8; ++n) {
                bfv8 vf = *(const bfv8*)&Vs[n * 16 + lm][k2 * 32 + lg * 8];
                o[n] = __builtin_amdgcn_mfma_f32_16x16x32_bf16(pa, vf, o[n], 0, 0, 0);
            }
        }
    }
    // epilogue: bf16 out, rows qi0+r, cols h*128 + n*16 + lm
    float invl[4];
#pragma unroll
    for (int r = 0; r < 4; ++r) invl[r] = 1.0f / lrow[r];
    unsigned short* op = ob + (size_t)(b * SEQ + qi0) * DMODEL + h * HEADD + lm;
#pragma unroll
    for (int n = 0; n < 8; ++n)
#pragma unroll
        for (int r = 0; r < 4; ++r)
            op[(size_t)r * DMODEL + n * 16] = f2bf(o[n][r] * invl[r]);
}

// ---------- launch ----------
extern "C" void kernel_launch(void* const* d_in, const int* in_sizes, int n_in,
                              void* d_out, int out_size, void* d_ws, size_t ws_size,
                              hipStream_t stream) {
    const float* x   = (const float*)d_in[0];
    const float* wq  = (const float*)d_in[1];
    const float* wk  = (const float*)d_in[2];
    const float* wv  = (const float*)d_in[3];
    const float* wo  = (const float*)d_in[4];
    const float* qnw = (const float*)d_in[5];
    const float* knw = (const float*)d_in[6];
    const int*   wsz = (const int*)d_in[7];
    float* out = (float*)d_out;

    // workspace layout (136 MB total)
    char* ws = (char*)d_ws;
    unsigned short* xb  = (unsigned short*)(ws);                 // 16.78 MB (x bf16; reused for attn out)
    unsigned short* w1  = (unsigned short*)(ws + 16777216);      // 8.39 MB (wq, later wo)
    unsigned short* w2  = (unsigned short*)(ws + 25165824);      // wk
    unsigned short* w3  = (unsigned short*)(ws + 33554432);      // wv
    float* qf           = (float*)(ws + 41943040);               // 33.55 MB fp32 Q
    float* kf           = (float*)(ws + 75497472);               // 33.55 MB fp32 K
    unsigned short* qbf = (unsigned short*)(ws + 109051904);     // 16.78 MB bf16 Q (rope+LN)
    unsigned short* vtb = (unsigned short*)(ws + 125829120);     // 16.78 MB bf16 V transposed
    unsigned short* kbf = (unsigned short*)(ws + 41943040);      // reuses qf after rope_q

    cvt_f2b<<<8192, 256, 0, stream>>>(x,  xb, MROWS * DMODEL);
    cvt_f2b<<<4096, 256, 0, stream>>>(wq, w1, DMODEL * DMODEL);
    cvt_f2b<<<4096, 256, 0, stream>>>(wk, w2, DMODEL * DMODEL);
    cvt_f2b<<<4096, 256, 0, stream>>>(wv, w3, DMODEL * DMODEL);

    dim3 gg(DMODEL / GBN, MROWS / GBM);   // (16, 32)
    gemm_bt_bf16<<<gg, 256, 0, stream>>>(xb, w1, qf, MROWS, DMODEL, DMODEL);
    gemm_bt_bf16<<<gg, 256, 0, stream>>>(xb, w2, kf, MROWS, DMODEL, DMODEL);
    gemm_bt_vt  <<<gg, 256, 0, stream>>>(xb, w3, vtb, MROWS, DMODEL, DMODEL);

    cvt_f2b<<<4096, 256, 0, stream>>>(wo, w1, DMODEL * DMODEL);  // w1 free after Q GEMM

    rope_ln_b<<<MROWS * NHEADS / 4, 256, 0, stream>>>(qf, qnw, qbf);
    rope_ln_b<<<MROWS * NHEADS / 4, 256, 0, stream>>>(kf, knw, kbf);  // kbf overlays qf (consumed)

    attn_mfma<<<dim3(SEQ / AQT, NHEADS, BATCH), 256, 0, stream>>>(qbf, kbf, vtb, xb, wsz);

    gemm_bt_bf16<<<gg, 256, 0, stream>>>(xb, w1, out, MROWS, DMODEL, DMODEL);
}

// Round 3
// 522.697 us; speedup vs baseline: 3.7376x; 1.8687x over previous
//
#include <hip/hip_runtime.h>

// ---------- common ----------
typedef __bf16 bfv8 __attribute__((ext_vector_type(8)));
typedef float f32x4 __attribute__((ext_vector_type(4)));

#define DMODEL 2048
#define NHEADS 16
#define HEADD 128
#define SEQ 2048
#define BATCH 2
#define MROWS (BATCH * SEQ)   // 4096

__device__ __forceinline__ unsigned short f2bf(float f) {
    unsigned int x = __float_as_uint(f);
    x += 0x7fffu + ((x >> 16) & 1u);   // round-to-nearest-even
    return (unsigned short)(x >> 16);
}

// ---------- fp32 -> bf16 convert ----------
__global__ __launch_bounds__(256) void cvt_f2b(const float* __restrict__ s,
                                               unsigned short* __restrict__ d, int n) {
    int i = (blockIdx.x * 256 + threadIdx.x) * 4;
    if (i >= n) return;
    float4 v = *(const float4*)(s + i);
    ushort4 o;
    o.x = f2bf(v.x); o.y = f2bf(v.y); o.z = f2bf(v.z); o.w = f2bf(v.w);
    *(ushort4*)(d + i) = o;
}

// ============================================================
// m97-style GEMM core: global_load_lds(16B) staging, XOR-swizzled
// unpadded LDS, 128x128 tile, BK=64, 4 waves, 16x16x32 bf16 MFMA.
// LDS layout: tile[m][c] (c = 16B chunk, 8/row) stores global chunk
// g = c ^ (m&7). Fragment read chunk (kk/8+lg) ^ (lr&7): each 8-lane
// group covers all 32 banks exactly once -> conflict-free.
// ============================================================
#define GBK 64

__device__ __forceinline__ void stage_tile(const unsigned short* __restrict__ gbase,
                                           unsigned short* lds, int ldK,
                                           int wave, int lane) {
#pragma unroll
    for (int i = 0; i < 4; ++i) {
        int L = wave * 256 + i * 64 + lane;     // 16B-chunk index in [0,1024)
        int m = L >> 3, c = L & 7;
        int g = c ^ (m & 7);
        const unsigned short* gp = gbase + (size_t)m * ldK + g * 8;
        __builtin_amdgcn_global_load_lds(
            (const __attribute__((address_space(1))) unsigned int*)gp,
            (__attribute__((address_space(3))) unsigned int*)(lds + (size_t)(wave * 256 + i * 64) * 8),
            16, 0, 0);
    }
}

// ---------- fused QKV GEMM: A[4096][2048] x Wcat[6144][2048]^T ----------
// N-region 0 -> Qf fp32, 1 -> Kf fp32, 2 -> V bf16 transposed per head
__global__ __launch_bounds__(256) void gemm_qkv(const unsigned short* __restrict__ A,
                                                const unsigned short* __restrict__ Bw,
                                                float* __restrict__ Qf,
                                                float* __restrict__ Kf,
                                                unsigned short* __restrict__ VT) {
    __shared__ unsigned short As[128][64];
    __shared__ unsigned short Bs[128][64];
    const int K = DMODEL;
    int tid  = threadIdx.x;
    int bm   = blockIdx.y * 128, bn = blockIdx.x * 128;
    int wave = tid >> 6, lane = tid & 63;
    int wm   = (wave >> 1) * 64, wn = (wave & 1) * 64;
    int lr   = lane & 15, lg = lane >> 4;

    f32x4 acc[4][4];
    f32x4 z = {0.f, 0.f, 0.f, 0.f};
#pragma unroll
    for (int i = 0; i < 4; ++i)
#pragma unroll
        for (int j = 0; j < 4; ++j) acc[i][j] = z;

    const unsigned short* Ab = A  + (size_t)bm * K;
    const unsigned short* Bb = Bw + (size_t)bn * K;

    for (int k0 = 0; k0 < K; k0 += GBK) {
        __syncthreads();   // previous iter's ds_reads done
        stage_tile(Ab + k0, &As[0][0], K, wave, lane);
        stage_tile(Bb + k0, &Bs[0][0], K, wave, lane);
        __syncthreads();   // DMA drained (vmcnt(0) at barrier)
#pragma unroll
        for (int kk = 0; kk < GBK; kk += 32) {
            int ck = (kk >> 3) + lg;
            bfv8 af[4], bf[4];
#pragma unroll
            for (int i = 0; i < 4; ++i)
                af[i] = *(const bfv8*)&As[wm + i * 16 + lr][(ck ^ (lr & 7)) * 8];
#pragma unroll
            for (int j = 0; j < 4; ++j)
                bf[j] = *(const bfv8*)&Bs[wn + j * 16 + lr][(ck ^ (lr & 7)) * 8];
#pragma unroll
            for (int i = 0; i < 4; ++i)
#pragma unroll
                for (int j = 0; j < 4; ++j)
                    acc[i][j] = __builtin_amdgcn_mfma_f32_16x16x32_bf16(af[i], bf[j], acc[i][j], 0, 0, 0);
        }
    }
    int orow0 = bm + wm + lg * 4;
    int region = bn >> 11;          // block-uniform: 0=Q 1=K 2=V
    int nloc   = bn & 2047;
    if (region < 2) {
        float* C = region ? Kf : Qf;
#pragma unroll
        for (int i = 0; i < 4; ++i)
#pragma unroll
            for (int j = 0; j < 4; ++j)
#pragma unroll
                for (int r = 0; r < 4; ++r)
                    C[(size_t)(orow0 + i * 16 + r) * DMODEL + nloc + wn + j * 16 + lr] = acc[i][j][r];
    } else {
#pragma unroll
        for (int i = 0; i < 4; ++i) {
            int row = orow0 + i * 16;
            int bb = row >> 11, ss = row & (SEQ - 1);
#pragma unroll
            for (int j = 0; j < 4; ++j) {
                int col = nloc + wn + j * 16 + lr;
                int hh = col >> 7, dd = col & (HEADD - 1);
                ushort4 o4;
                o4.x = f2bf(acc[i][j][0]);
                o4.y = f2bf(acc[i][j][1]);
                o4.z = f2bf(acc[i][j][2]);
                o4.w = f2bf(acc[i][j][3]);
                *(ushort4*)(VT + ((size_t)((bb * NHEADS + hh) * HEADD + dd)) * SEQ + ss) = o4;
            }
        }
    }
}

// ---------- plain GEMM (fp32 out): C[M][N] = A[M][K] * Bw[N][K]^T ----------
__global__ __launch_bounds__(256) void gemm_bt(const unsigned short* __restrict__ A,
                                               const unsigned short* __restrict__ Bw,
                                               float* __restrict__ C,
                                               int M, int N, int K) {
    __shared__ unsigned short As[128][64];
    __shared__ unsigned short Bs[128][64];
    int tid  = threadIdx.x;
    int bm   = blockIdx.y * 128, bn = blockIdx.x * 128;
    int wave = tid >> 6, lane = tid & 63;
    int wm   = (wave >> 1) * 64, wn = (wave & 1) * 64;
    int lr   = lane & 15, lg = lane >> 4;

    f32x4 acc[4][4];
    f32x4 z = {0.f, 0.f, 0.f, 0.f};
#pragma unroll
    for (int i = 0; i < 4; ++i)
#pragma unroll
        for (int j = 0; j < 4; ++j) acc[i][j] = z;

    const unsigned short* Ab = A  + (size_t)bm * K;
    const unsigned short* Bb = Bw + (size_t)bn * K;

    for (int k0 = 0; k0 < K; k0 += GBK) {
        __syncthreads();
        stage_tile(Ab + k0, &As[0][0], K, wave, lane);
        stage_tile(Bb + k0, &Bs[0][0], K, wave, lane);
        __syncthreads();
#pragma unroll
        for (int kk = 0; kk < GBK; kk += 32) {
            int ck = (kk >> 3) + lg;
            bfv8 af[4], bf[4];
#pragma unroll
            for (int i = 0; i < 4; ++i)
                af[i] = *(const bfv8*)&As[wm + i * 16 + lr][(ck ^ (lr & 7)) * 8];
#pragma unroll
            for (int j = 0; j < 4; ++j)
                bf[j] = *(const bfv8*)&Bs[wn + j * 16 + lr][(ck ^ (lr & 7)) * 8];
#pragma unroll
            for (int i = 0; i < 4; ++i)
#pragma unroll
                for (int j = 0; j < 4; ++j)
                    acc[i][j] = __builtin_amdgcn_mfma_f32_16x16x32_bf16(af[i], bf[j], acc[i][j], 0, 0, 0);
        }
    }
    int orow0 = bm + wm + lg * 4;
    int ocol0 = bn + wn + lr;
#pragma unroll
    for (int i = 0; i < 4; ++i)
#pragma unroll
        for (int j = 0; j < 4; ++j)
#pragma unroll
            for (int r = 0; r < 4; ++r)
                C[(size_t)(orow0 + i * 16 + r) * N + ocol0 + j * 16] = acc[i][j][r];
}

// ---------- RoPE + per-head LayerNorm: fp32 in -> bf16 out ----------
__global__ __launch_bounds__(256) void rope_ln_b(const float* __restrict__ t,
                                                 const float* __restrict__ w,
                                                 unsigned short* __restrict__ ob) {
    int gr   = blockIdx.x * 4 + (threadIdx.x >> 6);
    int lane = threadIdx.x & 63;
    int m = gr >> 4;
    int h = gr & 15;
    int s = m & (SEQ - 1);
    const float* p = t + (size_t)m * DMODEL + h * HEADD + lane * 2;
    float2 xv = *(const float2*)p;
    float inv = powf(10000.0f, -(float)lane * (1.0f / 64.0f));
    float ang = (float)s * inv;
    float sn, c;
    sincosf(ang, &sn, &c);
    float y0 = xv.x * c - xv.y * sn;
    float y1 = xv.x * sn + xv.y * c;
    float sum = y0 + y1;
    float sq  = y0 * y0 + y1 * y1;
#pragma unroll
    for (int o = 32; o >= 1; o >>= 1) {
        sum += __shfl_xor(sum, o);
        sq  += __shfl_xor(sq, o);
    }
    float mu  = sum * (1.0f / 128.0f);
    float var = sq * (1.0f / 128.0f) - mu * mu;
    float rs  = rsqrtf(var + 1e-5f);
    float2 wv = *(const float2*)(w + lane * 2);
    ushort2 ov;
    ov.x = f2bf((y0 - mu) * rs * wv.x);
    ov.y = f2bf((y1 - mu) * rs * wv.y);
    *(ushort2*)(ob + (size_t)m * DMODEL + h * HEADD + lane * 2) = ov;
}

// ---------- bf16 MFMA flash attention (sliding window) ----------
#define AQT 64
#define AKT 64
#define KSP 136   // 128+8 pad
#define VTP 72    // 64+8 pad
#define PSP 72    // 64+8 pad

__global__ __launch_bounds__(256) void attn_mfma(const unsigned short* __restrict__ qb,
                                                 const unsigned short* __restrict__ kb,
                                                 const unsigned short* __restrict__ vt,
                                                 unsigned short* __restrict__ ob,
                                                 const int* __restrict__ wptr) {
    __shared__ unsigned short Ks[AKT][KSP];
    __shared__ unsigned short Vs[HEADD][VTP];
    __shared__ unsigned short Ps[4][16][PSP];
    int tid  = threadIdx.x;
    int wq   = tid >> 6, lane = tid & 63;
    int lm   = lane & 15, lg = lane >> 4;
    int b = blockIdx.z, h = blockIdx.y;
    int q0 = blockIdx.x * AQT;
    int W = *wptr;

    bfv8 qa[4];
    {
        const unsigned short* qp = qb + (size_t)(b * SEQ + q0 + wq * 16 + lm) * DMODEL + h * HEADD + lg * 8;
#pragma unroll
        for (int kk = 0; kk < 4; ++kk) qa[kk] = *(const bfv8*)(qp + kk * 32);
    }

    f32x4 o[8];
    f32x4 z = {0.f, 0.f, 0.f, 0.f};
#pragma unroll
    for (int n = 0; n < 8; ++n) o[n] = z;
    float mrow[4], lrow[4];
#pragma unroll
    for (int r = 0; r < 4; ++r) { mrow[r] = -1e30f; lrow[r] = 0.f; }

    const unsigned short* kbase = kb + (size_t)(b * SEQ) * DMODEL + h * HEADD;
    const unsigned short* vbase = vt + (size_t)((b * NHEADS + h) * HEADD) * SEQ;

    int kt_lo = max(0, q0 - W) & ~(AKT - 1);
    const float scale = 0.08838834764831845f;
    int qi0 = q0 + wq * 16 + lg * 4;

    for (int kt = kt_lo; kt < q0 + AQT; kt += AKT) {
        __syncthreads();
#pragma unroll
        for (int i = 0; i < 4; ++i) {
            int c = i * 256 + tid;
            int row = c >> 4, ch = c & 15;
            *(int4*)&Ks[row][ch * 8] = *(const int4*)(kbase + (size_t)(kt + row) * DMODEL + ch * 8);
        }
#pragma unroll
        for (int i = 0; i < 4; ++i) {
            int c = i * 256 + tid;
            int row = c >> 3, ch = c & 7;
            *(int4*)&Vs[row][ch * 8] = *(const int4*)(vbase + (size_t)row * SEQ + kt + ch * 8);
        }
        __syncthreads();

        f32x4 s[4];
#pragma unroll
        for (int j = 0; j < 4; ++j) s[j] = z;
#pragma unroll
        for (int j = 0; j < 4; ++j)
#pragma unroll
            for (int kk = 0; kk < 4; ++kk) {
                bfv8 kf = *(const bfv8*)&Ks[j * 16 + lm][kk * 32 + lg * 8];
                s[j] = __builtin_amdgcn_mfma_f32_16x16x32_bf16(qa[kk], kf, s[j], 0, 0, 0);
            }
#pragma unroll
        for (int j = 0; j < 4; ++j) {
            int kj = kt + j * 16 + lm;
#pragma unroll
            for (int r = 0; r < 4; ++r) {
                bool ok = (kj <= qi0 + r) && (kj >= qi0 + r - W);
                s[j][r] = ok ? s[j][r] * scale : -1e30f;
            }
        }
        float mx[4];
#pragma unroll
        for (int r = 0; r < 4; ++r)
            mx[r] = fmaxf(fmaxf(s[0][r], s[1][r]), fmaxf(s[2][r], s[3][r]));
#pragma unroll
        for (int msk = 1; msk <= 8; msk <<= 1)
#pragma unroll
            for (int r = 0; r < 4; ++r) mx[r] = fmaxf(mx[r], __shfl_xor(mx[r], msk));
        float alpha[4];
#pragma unroll
        for (int r = 0; r < 4; ++r) {
            float mnew = fmaxf(mrow[r], mx[r]);
            alpha[r] = __expf(mrow[r] - mnew);
            mrow[r] = mnew;
        }
        float rsum[4] = {0.f, 0.f, 0.f, 0.f};
#pragma unroll
        for (int j = 0; j < 4; ++j)
#pragma unroll
            for (int r = 0; r < 4; ++r) {
                float p = __expf(s[j][r] - mrow[r]);
                rsum[r] += p;
                Ps[wq][lg * 4 + r][j * 16 + lm] = f2bf(p);
            }
#pragma unroll
        for (int msk = 1; msk <= 8; msk <<= 1)
#pragma unroll
            for (int r = 0; r < 4; ++r) rsum[r] += __shfl_xor(rsum[r], msk);
#pragma unroll
        for (int r = 0; r < 4; ++r) lrow[r] = lrow[r] * alpha[r] + rsum[r];
#pragma unroll
        for (int n = 0; n < 8; ++n)
#pragma unroll
            for (int r = 0; r < 4; ++r) o[n][r] *= alpha[r];
#pragma unroll
        for (int k2 = 0; k2 < 2; ++k2) {
            bfv8 pa = *(const bfv8*)&Ps[wq][lm][k2 * 32 + lg * 8];
#pragma unroll
            for (int n = 0; n < 8; ++n) {
                bfv8 vf = *(const bfv8*)&Vs[n * 16 + lm][k2 * 32 + lg * 8];
                o[n] = __builtin_amdgcn_mfma_f32_16x16x32_bf16(pa, vf, o[n], 0, 0, 0);
            }
        }
    }
    float invl[4];
#pragma unroll
    for (int r = 0; r < 4; ++r) invl[r] = 1.0f / lrow[r];
    unsigned short* op = ob + (size_t)(b * SEQ + qi0) * DMODEL + h * HEADD + lm;
#pragma unroll
    for (int n = 0; n < 8; ++n)
#pragma unroll
        for (int r = 0; r < 4; ++r)
            op[(size_t)r * DMODEL + n * 16] = f2bf(o[n][r] * invl[r]);
}

// ---------- launch ----------
extern "C" void kernel_launch(void* const* d_in, const int* in_sizes, int n_in,
                              void* d_out, int out_size, void* d_ws, size_t ws_size,
                              hipStream_t stream) {
    const float* x   = (const float*)d_in[0];
    const float* wq  = (const float*)d_in[1];
    const float* wk  = (const float*)d_in[2];
    const float* wv  = (const float*)d_in[3];
    const float* wo  = (const float*)d_in[4];
    const float* qnw = (const float*)d_in[5];
    const float* knw = (const float*)d_in[6];
    const int*   wsz = (const int*)d_in[7];
    float* out = (float*)d_out;

    // workspace layout (151 MB total)
    char* ws = (char*)d_ws;
    unsigned short* xb  = (unsigned short*)(ws);                 // 16.78 MB (x bf16; reused for attn out)
    unsigned short* w1  = (unsigned short*)(ws + 16777216);      // wq \  contiguous ->
    unsigned short* w2  = (unsigned short*)(ws + 25165824);      // wk  > Wcat [6144][2048]
    unsigned short* w3  = (unsigned short*)(ws + 33554432);      // wv /
    unsigned short* w4  = (unsigned short*)(ws + 41943040);      // wo
    float* qf           = (float*)(ws + 50331648);               // 33.55 MB fp32 Q
    float* kf           = (float*)(ws + 83886080);               // 33.55 MB fp32 K
    unsigned short* qbf = (unsigned short*)(ws + 117440512);     // 16.78 MB bf16 Q
    unsigned short* vtb = (unsigned short*)(ws + 134217728);     // 16.78 MB bf16 V^T
    unsigned short* kbf = (unsigned short*)(ws + 50331648);      // overlays qf (consumed before write)

    cvt_f2b<<<8192, 256, 0, stream>>>(x,  xb, MROWS * DMODEL);
    cvt_f2b<<<4096, 256, 0, stream>>>(wq, w1, DMODEL * DMODEL);
    cvt_f2b<<<4096, 256, 0, stream>>>(wk, w2, DMODEL * DMODEL);
    cvt_f2b<<<4096, 256, 0, stream>>>(wv, w3, DMODEL * DMODEL);
    cvt_f2b<<<4096, 256, 0, stream>>>(wo, w4, DMODEL * DMODEL);

    gemm_qkv<<<dim3(3 * DMODEL / 128, MROWS / 128), 256, 0, stream>>>(xb, w1, qf, kf, vtb);

    rope_ln_b<<<MROWS * NHEADS / 4, 256, 0, stream>>>(qf, qnw, qbf);
    rope_ln_b<<<MROWS * NHEADS / 4, 256, 0, stream>>>(kf, knw, kbf);

    attn_mfma<<<dim3(SEQ / AQT, NHEADS, BATCH), 256, 0, stream>>>(qbf, kbf, vtb, xb, wsz);

    gemm_bt<<<dim3(DMODEL / 128, MROWS / 128), 256, 0, stream>>>(xb, w4, out, MROWS, DMODEL, DMODEL);
}

// Round 4
// 439.758 us; speedup vs baseline: 4.4425x; 1.1886x over previous
//
#include <hip/hip_runtime.h>

// ---------- common ----------
typedef __bf16 bfv8 __attribute__((ext_vector_type(8)));
typedef float f32x4 __attribute__((ext_vector_type(4)));

#define DMODEL 2048
#define NHEADS 16
#define HEADD 128
#define SEQ 2048
#define BATCH 2
#define MROWS (BATCH * SEQ)   // 4096

__device__ __forceinline__ unsigned short f2bf(float f) {
    unsigned int x = __float_as_uint(f);
    x += 0x7fffu + ((x >> 16) & 1u);   // round-to-nearest-even
    return (unsigned short)(x >> 16);
}
__device__ __forceinline__ float bf2f(unsigned short u) {
    return __uint_as_float((unsigned int)u << 16);
}
__device__ __forceinline__ unsigned int pk2(float a, float b) {
    return (unsigned int)f2bf(a) | ((unsigned int)f2bf(b) << 16);
}

// ---------- fp32 -> bf16 convert ----------
__global__ __launch_bounds__(256) void cvt_f2b(const float* __restrict__ s,
                                               unsigned short* __restrict__ d, int n) {
    int i = (blockIdx.x * 256 + threadIdx.x) * 4;
    if (i >= n) return;
    float4 v = *(const float4*)(s + i);
    ushort4 o;
    o.x = f2bf(v.x); o.y = f2bf(v.y); o.z = f2bf(v.z); o.w = f2bf(v.w);
    *(ushort4*)(d + i) = o;
}

// ============================================================
// global_load_lds staging into XOR-swizzled unpadded LDS.
// CPRL = log2(16B-chunks per row). Stored chunk c holds global
// chunk g = c ^ (row & 7). 4x64 chunks per call = 4 KB.
// ============================================================
template <int CPRL>
__device__ __forceinline__ void stage_t(const unsigned short* __restrict__ gbase,
                                        unsigned short* lds, size_t strideShorts,
                                        int wave, int lane) {
#pragma unroll
    for (int i = 0; i < 4; ++i) {
        int L = wave * 256 + i * 64 + lane;
        int m = L >> CPRL, c = L & ((1 << CPRL) - 1);
        int g = c ^ (m & 7);
        const unsigned short* gp = gbase + (size_t)m * strideShorts + g * 8;
        __builtin_amdgcn_global_load_lds(
            (const __attribute__((address_space(1))) unsigned int*)gp,
            (__attribute__((address_space(3))) unsigned int*)(lds + (size_t)(wave * 256 + i * 64) * 8),
            16, 0, 0);
    }
}

#define GBK 64

// ---------- fused QKV GEMM: A[4096][2048] x Wcat[6144][2048]^T ----------
// N-region 0 -> Q bf16, 1 -> K bf16, 2 -> V bf16 transposed per head
__global__ __launch_bounds__(256) void gemm_qkv(const unsigned short* __restrict__ A,
                                                const unsigned short* __restrict__ Bw,
                                                unsigned short* __restrict__ Qb,
                                                unsigned short* __restrict__ Kb,
                                                unsigned short* __restrict__ VT) {
    __shared__ __align__(16) unsigned short As[128 * 64];
    __shared__ __align__(16) unsigned short Bs[128 * 64];
    const int K = DMODEL;
    int tid  = threadIdx.x;
    int bm   = blockIdx.y * 128, bn = blockIdx.x * 128;
    int wave = tid >> 6, lane = tid & 63;
    int wm   = (wave >> 1) * 64, wn = (wave & 1) * 64;
    int lr   = lane & 15, lg = lane >> 4;

    f32x4 acc[4][4];
    f32x4 z = {0.f, 0.f, 0.f, 0.f};
#pragma unroll
    for (int i = 0; i < 4; ++i)
#pragma unroll
        for (int j = 0; j < 4; ++j) acc[i][j] = z;

    const unsigned short* Ab = A  + (size_t)bm * K;
    const unsigned short* Bb = Bw + (size_t)bn * K;

    for (int k0 = 0; k0 < K; k0 += GBK) {
        __syncthreads();
        stage_t<3>(Ab + k0, As, K, wave, lane);
        stage_t<3>(Bb + k0, Bs, K, wave, lane);
        __syncthreads();
#pragma unroll
        for (int kk = 0; kk < GBK; kk += 32) {
            int ck = (kk >> 3) + lg;
            bfv8 af[4], bf[4];
#pragma unroll
            for (int i = 0; i < 4; ++i)
                af[i] = *(const bfv8*)&As[(wm + i * 16 + lr) * 64 + ((ck ^ (lr & 7))) * 8];
#pragma unroll
            for (int j = 0; j < 4; ++j)
                bf[j] = *(const bfv8*)&Bs[(wn + j * 16 + lr) * 64 + ((ck ^ (lr & 7))) * 8];
#pragma unroll
            for (int i = 0; i < 4; ++i)
#pragma unroll
                for (int j = 0; j < 4; ++j)
                    acc[i][j] = __builtin_amdgcn_mfma_f32_16x16x32_bf16(af[i], bf[j], acc[i][j], 0, 0, 0);
        }
    }
    int orow0 = bm + wm + lg * 4;
    int region = bn >> 11;          // block-uniform: 0=Q 1=K 2=V
    int nloc   = bn & 2047;
    if (region < 2) {
        unsigned short* C = region ? Kb : Qb;
#pragma unroll
        for (int i = 0; i < 4; ++i)
#pragma unroll
            for (int j = 0; j < 4; ++j)
#pragma unroll
                for (int r = 0; r < 4; ++r)
                    C[(size_t)(orow0 + i * 16 + r) * DMODEL + nloc + wn + j * 16 + lr] = f2bf(acc[i][j][r]);
    } else {
#pragma unroll
        for (int i = 0; i < 4; ++i) {
            int row = orow0 + i * 16;
            int bb = row >> 11, ss = row & (SEQ - 1);
#pragma unroll
            for (int j = 0; j < 4; ++j) {
                int col = nloc + wn + j * 16 + lr;
                int hh = col >> 7, dd = col & (HEADD - 1);
                ushort4 o4;
                o4.x = f2bf(acc[i][j][0]);
                o4.y = f2bf(acc[i][j][1]);
                o4.z = f2bf(acc[i][j][2]);
                o4.w = f2bf(acc[i][j][3]);
                *(ushort4*)(VT + ((size_t)((bb * NHEADS + hh) * HEADD + dd)) * SEQ + ss) = o4;
            }
        }
    }
}

// ---------- plain GEMM (fp32 out): C[M][N] = A[M][K] * Bw[N][K]^T ----------
__global__ __launch_bounds__(256) void gemm_bt(const unsigned short* __restrict__ A,
                                               const unsigned short* __restrict__ Bw,
                                               float* __restrict__ C,
                                               int M, int N, int K) {
    __shared__ __align__(16) unsigned short As[128 * 64];
    __shared__ __align__(16) unsigned short Bs[128 * 64];
    int tid  = threadIdx.x;
    int bm   = blockIdx.y * 128, bn = blockIdx.x * 128;
    int wave = tid >> 6, lane = tid & 63;
    int wm   = (wave >> 1) * 64, wn = (wave & 1) * 64;
    int lr   = lane & 15, lg = lane >> 4;

    f32x4 acc[4][4];
    f32x4 z = {0.f, 0.f, 0.f, 0.f};
#pragma unroll
    for (int i = 0; i < 4; ++i)
#pragma unroll
        for (int j = 0; j < 4; ++j) acc[i][j] = z;

    const unsigned short* Ab = A  + (size_t)bm * K;
    const unsigned short* Bb = Bw + (size_t)bn * K;

    for (int k0 = 0; k0 < K; k0 += GBK) {
        __syncthreads();
        stage_t<3>(Ab + k0, As, K, wave, lane);
        stage_t<3>(Bb + k0, Bs, K, wave, lane);
        __syncthreads();
#pragma unroll
        for (int kk = 0; kk < GBK; kk += 32) {
            int ck = (kk >> 3) + lg;
            bfv8 af[4], bf[4];
#pragma unroll
            for (int i = 0; i < 4; ++i)
                af[i] = *(const bfv8*)&As[(wm + i * 16 + lr) * 64 + ((ck ^ (lr & 7))) * 8];
#pragma unroll
            for (int j = 0; j < 4; ++j)
                bf[j] = *(const bfv8*)&Bs[(wn + j * 16 + lr) * 64 + ((ck ^ (lr & 7))) * 8];
#pragma unroll
            for (int i = 0; i < 4; ++i)
#pragma unroll
                for (int j = 0; j < 4; ++j)
                    acc[i][j] = __builtin_amdgcn_mfma_f32_16x16x32_bf16(af[i], bf[j], acc[i][j], 0, 0, 0);
        }
    }
    int orow0 = bm + wm + lg * 4;
    int ocol0 = bn + wn + lr;
#pragma unroll
    for (int i = 0; i < 4; ++i)
#pragma unroll
        for (int j = 0; j < 4; ++j)
#pragma unroll
            for (int r = 0; r < 4; ++r)
                C[(size_t)(orow0 + i * 16 + r) * N + ocol0 + j * 16] = acc[i][j][r];
}

// ---------- RoPE + per-head LayerNorm, in-place on bf16; Q pre-scaled ----------
__global__ __launch_bounds__(256) void rope_ln_ip(unsigned short* __restrict__ qt,
                                                  unsigned short* __restrict__ kt,
                                                  const float* __restrict__ qw,
                                                  const float* __restrict__ kw) {
    int which = blockIdx.y;
    unsigned short* t = which ? kt : qt;
    const float* w = which ? kw : qw;
    float scale = which ? 1.0f : 0.08838834764831845f;   // fold 1/sqrt(128) into Q
    int gr   = blockIdx.x * 4 + (threadIdx.x >> 6);
    int lane = threadIdx.x & 63;
    int m = gr >> 4;
    int h = gr & 15;
    int s = m & (SEQ - 1);
    unsigned short* p = t + (size_t)m * DMODEL + h * HEADD + lane * 2;
    ushort2 xv = *(const ushort2*)p;
    float x0 = bf2f(xv.x), x1 = bf2f(xv.y);
    float inv = powf(10000.0f, -(float)lane * (1.0f / 64.0f));
    float ang = (float)s * inv;
    float sn, c;
    sincosf(ang, &sn, &c);
    float y0 = x0 * c - x1 * sn;
    float y1 = x0 * sn + x1 * c;
    float sum = y0 + y1;
    float sq  = y0 * y0 + y1 * y1;
#pragma unroll
    for (int o = 32; o >= 1; o >>= 1) {
        sum += __shfl_xor(sum, o);
        sq  += __shfl_xor(sq, o);
    }
    float mu  = sum * (1.0f / 128.0f);
    float var = sq * (1.0f / 128.0f) - mu * mu;
    float rs  = rsqrtf(var + 1e-5f) * scale;
    float2 wv = *(const float2*)(w + lane * 2);
    ushort2 ov;
    ov.x = f2bf((y0 - mu) * rs * wv.x);
    ov.y = f2bf((y1 - mu) * rs * wv.y);
    *(ushort2*)p = ov;
}

// ---------- bf16 MFMA flash attention (sliding window), S^T compute ----------
#define AQT 64
#define AKT 64

__global__ __launch_bounds__(256) void attn_mfma(const unsigned short* __restrict__ qb,
                                                 const unsigned short* __restrict__ kb,
                                                 const unsigned short* __restrict__ vt,
                                                 unsigned short* __restrict__ ob,
                                                 const int* __restrict__ wptr) {
    __shared__ __align__(16) unsigned short Ks[64 * 128];    // K tile, swizzled, 16 KB
    __shared__ __align__(16) unsigned short Vs[128 * 64];    // V^T tile, swizzled, 16 KB
    __shared__ __align__(16) unsigned short Ps[4 * 16 * 64]; // per-wave P, swizzled, 8 KB
    int tid  = threadIdx.x;
    int wq   = tid >> 6, lane = tid & 63;
    int lm   = lane & 15, lg = lane >> 4;
    int lm7  = lm & 7;
    // XCD-grouped, heavy-first scheduling
    int gid  = blockIdx.x;
    int xcd  = gid & 7, slot = gid >> 3;
    int bh   = xcd * 4 + (slot >> 5);
    int b    = bh >> 4, h = bh & 15;
    int q0   = (31 - (slot & 31)) * AQT;
    int W    = *wptr;
    unsigned short* PsW = &Ps[wq * 1024];

    // Q B-fragments (16 queries/wave); Q already has 1/sqrt(d) folded in
    bfv8 qa[4];
    {
        const unsigned short* qp = qb + (size_t)(b * SEQ + q0 + wq * 16 + lm) * DMODEL + h * HEADD + lg * 8;
#pragma unroll
        for (int kk = 0; kk < 4; ++kk) qa[kk] = *(const bfv8*)(qp + kk * 32);
    }

    f32x4 o[8];
    f32x4 z = {0.f, 0.f, 0.f, 0.f};
#pragma unroll
    for (int n = 0; n < 8; ++n) o[n] = z;
    float mrow = -1e30f, lrow = 0.f;   // per-lane state for query lm (replicated over lg)

    const unsigned short* kbase = kb + (size_t)(b * SEQ) * DMODEL + h * HEADD;
    const unsigned short* vbase = vt + (size_t)((b * NHEADS + h) * HEADD) * SEQ;

    int kt_lo = max(0, q0 - W) & ~(AKT - 1);
    int qi = q0 + wq * 16 + lm;

    for (int kt = kt_lo; kt < q0 + AQT; kt += AKT) {
        __syncthreads();
        stage_t<4>(kbase + (size_t)kt * DMODEL, Ks, DMODEL, wq, lane);  // 64 x 128
        stage_t<3>(vbase + kt, Vs, SEQ, wq, lane);                      // 128 x 64
        __syncthreads();

        // S^T = K Q^T : D[m=key][n=query], 64x16 per wave
        f32x4 s[4];
#pragma unroll
        for (int j = 0; j < 4; ++j) s[j] = z;
#pragma unroll
        for (int kk = 0; kk < 4; ++kk) {
#pragma unroll
            for (int j = 0; j < 4; ++j) {
                int ck = (kk * 4 + lg) ^ lm7;
                bfv8 af = *(const bfv8*)&Ks[(j * 16 + lm) * 128 + ck * 8];
                s[j] = __builtin_amdgcn_mfma_f32_16x16x32_bf16(af, qa[kk], s[j], 0, 0, 0);
            }
        }
        // mask only edge tiles (wave-uniform branch)
        if ((kt + 63 >= q0) || (kt < q0 + 63 - W)) {
#pragma unroll
            for (int j = 0; j < 4; ++j) {
                int kj0 = kt + j * 16 + lg * 4;
#pragma unroll
                for (int r = 0; r < 4; ++r) {
                    bool ok = (kj0 + r <= qi) && (kj0 + r >= qi - W);
                    s[j][r] = ok ? s[j][r] : -1e30f;
                }
            }
        }
        // online softmax: one query per lane, reduce across lg (masks 16, 32)
        float mx = -1e30f;
#pragma unroll
        for (int j = 0; j < 4; ++j)
#pragma unroll
            for (int r = 0; r < 4; ++r) mx = fmaxf(mx, s[j][r]);
        mx = fmaxf(mx, __shfl_xor(mx, 16));
        mx = fmaxf(mx, __shfl_xor(mx, 32));
        float mnew  = fmaxf(mrow, mx);
        float alpha = __expf(mrow - mnew);
        mrow = mnew;
        float ls = 0.f;
#pragma unroll
        for (int j = 0; j < 4; ++j) {
            float p0 = __expf(s[j][0] - mnew);
            float p1 = __expf(s[j][1] - mnew);
            float p2 = __expf(s[j][2] - mnew);
            float p3 = __expf(s[j][3] - mnew);
            ls += (p0 + p1) + (p2 + p3);
            // P^T C-layout rows = 4 consecutive keys -> one packed b64 store
            int c0 = (j * 2 + (lg >> 1)) ^ lm7;
            uint2 wv;
            wv.x = pk2(p0, p1);
            wv.y = pk2(p2, p3);
            *(uint2*)&PsW[lm * 64 + c0 * 8 + (lg & 1) * 4] = wv;
        }
        ls += __shfl_xor(ls, 16);
        ls += __shfl_xor(ls, 32);
        lrow = lrow * alpha + ls;
        // broadcast alpha from softmax layout (query=lm) to O layout (query=lg*4+r)
        float al[4];
#pragma unroll
        for (int r = 0; r < 4; ++r) al[r] = __shfl(alpha, lg * 4 + r);
#pragma unroll
        for (int n = 0; n < 8; ++n)
#pragma unroll
            for (int r = 0; r < 4; ++r) o[n][r] *= al[r];
        // O += P V : A = P (wave-private LDS, same-wave ordering), B = V^T
#pragma unroll
        for (int k2 = 0; k2 < 2; ++k2) {
            int cc = (k2 * 4 + lg) ^ lm7;
            bfv8 pa = *(const bfv8*)&PsW[lm * 64 + cc * 8];
#pragma unroll
            for (int n = 0; n < 8; ++n) {
                bfv8 vf = *(const bfv8*)&Vs[(n * 16 + lm) * 64 + cc * 8];
                o[n] = __builtin_amdgcn_mfma_f32_16x16x32_bf16(pa, vf, o[n], 0, 0, 0);
            }
        }
    }
    // epilogue
    float linv[4];
#pragma unroll
    for (int r = 0; r < 4; ++r) linv[r] = 1.0f / __shfl(lrow, lg * 4 + r);
    int qrow = q0 + wq * 16 + lg * 4;
    unsigned short* op = ob + (size_t)(b * SEQ + qrow) * DMODEL + h * HEADD + lm;
#pragma unroll
    for (int n = 0; n < 8; ++n)
#pragma unroll
        for (int r = 0; r < 4; ++r)
            op[(size_t)r * DMODEL + n * 16] = f2bf(o[n][r] * linv[r]);
}

// ---------- launch ----------
extern "C" void kernel_launch(void* const* d_in, const int* in_sizes, int n_in,
                              void* d_out, int out_size, void* d_ws, size_t ws_size,
                              hipStream_t stream) {
    const float* x   = (const float*)d_in[0];
    const float* wq  = (const float*)d_in[1];
    const float* wk  = (const float*)d_in[2];
    const float* wv  = (const float*)d_in[3];
    const float* wo  = (const float*)d_in[4];
    const float* qnw = (const float*)d_in[5];
    const float* knw = (const float*)d_in[6];
    const int*   wsz = (const int*)d_in[7];
    float* out = (float*)d_out;

    // workspace layout (~101 MB)
    char* ws = (char*)d_ws;
    unsigned short* xb  = (unsigned short*)(ws);                 // 16.78 MB (x bf16; reused for attn out)
    unsigned short* w1  = (unsigned short*)(ws + 16777216);      // wq \  contiguous ->
    unsigned short* w2  = (unsigned short*)(ws + 25165824);      // wk  > Wcat [6144][2048]
    unsigned short* w3  = (unsigned short*)(ws + 33554432);      // wv /
    unsigned short* w4  = (unsigned short*)(ws + 41943040);      // wo
    unsigned short* qbf = (unsigned short*)(ws + 50331648);      // 16.78 MB bf16 Q
    unsigned short* kbf = (unsigned short*)(ws + 67108864);      // 16.78 MB bf16 K
    unsigned short* vtb = (unsigned short*)(ws + 83886080);      // 16.78 MB bf16 V^T

    cvt_f2b<<<8192, 256, 0, stream>>>(x,  xb, MROWS * DMODEL);
    cvt_f2b<<<4096, 256, 0, stream>>>(wq, w1, DMODEL * DMODEL);
    cvt_f2b<<<4096, 256, 0, stream>>>(wk, w2, DMODEL * DMODEL);
    cvt_f2b<<<4096, 256, 0, stream>>>(wv, w3, DMODEL * DMODEL);
    cvt_f2b<<<4096, 256, 0, stream>>>(wo, w4, DMODEL * DMODEL);

    gemm_qkv<<<dim3(3 * DMODEL / 128, MROWS / 128), 256, 0, stream>>>(xb, w1, qbf, kbf, vtb);

    rope_ln_ip<<<dim3(MROWS * NHEADS / 4, 2), 256, 0, stream>>>(qbf, kbf, qnw, knw);

    attn_mfma<<<(SEQ / AQT) * NHEADS * BATCH, 256, 0, stream>>>(qbf, kbf, vtb, xb, wsz);

    gemm_bt<<<dim3(DMODEL / 128, MROWS / 128), 256, 0, stream>>>(xb, w4, out, MROWS, DMODEL, DMODEL);
}